// Round 3
// baseline (321.112 us; speedup 1.0000x reference)
//
#include <hip/hip_runtime.h>
#include <cmath>

#define LN_EPS 1e-5f

typedef float  f32x4  __attribute__((ext_vector_type(4)));
typedef short  short8 __attribute__((ext_vector_type(8)));
typedef unsigned int uint4v __attribute__((ext_vector_type(4)));

// ws layout (uint offsets):
//   w1f  : [0, 2560*4)          B-frag bf16 (5kt x 8nt x 64 lanes, uint4 each)
//   w2f  : [10240, 10240+2048*4) (4kt x 8nt x 64)
//   sums : uint 18432..18436     (Sw,Sb,Sww,Swb,Sbb)
//   emb16: uint 18440..          (NUM_TYPES*128 bf16, row-major)
#define W1F_U4 2560
#define W2F_U4 2048
#define SUMS_U 18432
#define EMB_U  18440

__device__ __forceinline__ unsigned short f32_bf16_rne(float f) {
    union { float f; unsigned u; } v; v.f = f;
    unsigned r = v.u + 0x7FFFu + ((v.u >> 16) & 1u);
    return (unsigned short)(r >> 16);
}

// exact-erf GELU via Abramowitz&Stegun 7.1.26 (|err| <= 1.5e-7)
__device__ __forceinline__ float gelu_f(float x) {
    float ax = fabsf(x);
    float a  = ax * 0.70710678118654752f;
    float t  = __builtin_amdgcn_rcpf(fmaf(0.3275911f, a, 1.0f));
    float p  = t * fmaf(t, fmaf(t, fmaf(t, fmaf(t, 1.061405429f, -1.453152027f),
                                        1.421413741f), -0.284496736f), 0.254829592f);
    float e  = __builtin_amdgcn_exp2f(-1.44269504089f * a * a);
    float E  = fmaf(-p, e, 1.0f);
    return 0.5f * fmaf(ax, E, x);
}

__global__ void prep_kernel(const float* __restrict__ w1, const float* __restrict__ w2,
                            const float* __restrict__ emb,
                            const float* __restrict__ tp_w, const float* __restrict__ tp_b,
                            float* __restrict__ out,
                            unsigned* __restrict__ ws, int emb_pairs, int out4) {
    const int tid = blockIdx.x * 256 + threadIdx.x;
    const int NT  = gridDim.x * 256;
    uint4v* w1f = (uint4v*)ws;
    uint4v* w2f = w1f + W1F_U4;
    float*  sums = (float*)(ws + SUMS_U);
    unsigned* emb16 = ws + EMB_U;

    for (int i = tid; i < W1F_U4; i += NT) {
        const int lane = i & 63, nt = (i >> 6) & 7, kt = i >> 9;
        const int k0 = kt * 32 + (lane >> 4) * 8, n = nt * 16 + (lane & 15);
        uint4v r;
        #pragma unroll
        for (int j2 = 0; j2 < 4; ++j2) {
            unsigned lo = f32_bf16_rne(w1[(k0 + 2 * j2) * 128 + n]);
            unsigned hi = f32_bf16_rne(w1[(k0 + 2 * j2 + 1) * 128 + n]);
            r[j2] = lo | (hi << 16);
        }
        w1f[i] = r;
    }
    for (int i = tid; i < W2F_U4; i += NT) {
        const int lane = i & 63, nt = (i >> 6) & 7, kt = i >> 9;
        const int k0 = kt * 32 + (lane >> 4) * 8, n = nt * 16 + (lane & 15);
        uint4v r;
        #pragma unroll
        for (int j2 = 0; j2 < 4; ++j2) {
            unsigned lo = f32_bf16_rne(w2[(k0 + 2 * j2) * 128 + n]);
            unsigned hi = f32_bf16_rne(w2[(k0 + 2 * j2 + 1) * 128 + n]);
            r[j2] = lo | (hi << 16);
        }
        w2f[i] = r;
    }
    for (int i = tid; i < emb_pairs; i += NT) {
        unsigned lo = f32_bf16_rne(emb[2 * i]);
        unsigned hi = f32_bf16_rne(emb[2 * i + 1]);
        emb16[i] = lo | (hi << 16);
    }
    f32x4 z = {0.f, 0.f, 0.f, 0.f};
    for (int i = tid; i < out4; i += NT) ((f32x4*)out)[i] = z;

    // temporal-LN closed-form sums, once
    if (blockIdx.x == 0 && threadIdx.x < 64) {
        const int lane = threadIdx.x;
        float w = 0.f, bb = 0.f;
        if (lane < 32) { w = tp_w[lane]; bb = tp_b[lane]; }
        float s0 = w, s1 = bb, s2 = w * w, s3 = w * bb, s4 = bb * bb;
        #pragma unroll
        for (int m = 1; m < 64; m <<= 1) {
            s0 += __shfl_xor(s0, m); s1 += __shfl_xor(s1, m);
            s2 += __shfl_xor(s2, m); s3 += __shfl_xor(s3, m); s4 += __shfl_xor(s4, m);
        }
        if (lane == 0) { sums[0] = s0; sums[1] = s1; sums[2] = s2; sums[3] = s3; sums[4] = s4; }
    }
}

// One wave (64 threads) per block; block bid handles row b = bid>>2, positions [64w, 64w+64).
// Processes its 4 M-tiles in 2 groups of 2 to keep accumulator footprint at 64 regs.
__global__ __launch_bounds__(64, 3) void encoder_mfma(
    const int*   __restrict__ tids,  const float* __restrict__ dates,
    const int*   __restrict__ lengths,
    const float* __restrict__ tp_w,  const float* __restrict__ tp_b,
    const float* __restrict__ tp_lnw,const float* __restrict__ tp_lnb,
    const float* __restrict__ b1,    const float* __restrict__ ln1w, const float* __restrict__ ln1b,
    const float* __restrict__ b2,    const float* __restrict__ ln2w, const float* __restrict__ ln2b,
    const unsigned* __restrict__ ws, float* __restrict__ out, int L)
{
    // C->A transpose scratch, bank-swizzled rows; reused across the 2 groups. 8 KB.
    __shared__ unsigned short a2[2][4][64][8];

    const int bid  = blockIdx.x;
    const int b    = bid >> 2, w = bid & 3;
    const int lane = threadIdx.x;
    const int c = lane & 15, g = lane >> 4, h3 = c >> 3;
    const int len = min(max(lengths[b], 0), L);
    const int R0 = w * 64;
    if (R0 >= len) return;

    const uint4v* w1f = (const uint4v*)ws;
    const uint4v* w2f = w1f + W1F_U4;
    const float*  sums = (const float*)(ws + SUMS_U);
    const unsigned short* emb16 = (const unsigned short*)(ws + EMB_U);

    const float Sw = sums[0], Sb = sums[1], Sww = sums[2], Swb = sums[3], Sbb = sums[4];

    int id[4]; float dn[4]; bool amt[4];
    #pragma unroll
    for (int mt = 0; mt < 4; ++mt) {
        const int p  = R0 + mt * 16 + c;
        const int pc = min(p, L - 1);
        id[mt]  = tids[b * L + pc];
        dn[mt]  = dates[b * L + pc] * (1.f / 1825.f);
        amt[mt] = (R0 + mt * 16) < len;              // wave-uniform, monotone in mt
    }

    // temporal A-frags (row=c, k-chunk g*8..g*8+7)
    short8 tfrag[4];
    {
        float tw[8], tb[8], tlw[8], tlb[8];
        const int j0 = g * 8;
        #pragma unroll
        for (int jj = 0; jj < 8; ++jj) {
            tw[jj] = tp_w[j0 + jj];  tb[jj] = tp_b[j0 + jj];
            tlw[jj] = tp_lnw[j0 + jj]; tlb[jj] = tp_lnb[j0 + jj];
        }
        #pragma unroll
        for (int mt = 0; mt < 4; ++mt) {
            const float d  = dn[mt];
            const float tm = fmaf(d, Sw, Sb) * (1.f / 32.f);
            float tv = fmaf(d * d, Sww, fmaf(2.f * d, Swb, Sbb)) * (1.f / 32.f) - tm * tm;
            const float trs = rsqrtf(fmaxf(tv, 0.f) + LN_EPS);
            uint4v r;
            #pragma unroll
            for (int j2 = 0; j2 < 4; ++j2) {
                const float y0 = fmaf((fmaf(d, tw[2*j2],   tb[2*j2])   - tm) * trs, tlw[2*j2],   tlb[2*j2]);
                const float y1 = fmaf((fmaf(d, tw[2*j2+1], tb[2*j2+1]) - tm) * trs, tlw[2*j2+1], tlb[2*j2+1]);
                r[j2] = (unsigned)f32_bf16_rne(gelu_f(y0)) | ((unsigned)f32_bf16_rne(gelu_f(y1)) << 16);
            }
            union { uint4v u; short8 s; } cv; cv.u = r;
            tfrag[mt] = cv.s;
        }
    }

    float pool[8];
    #pragma unroll
    for (int nt = 0; nt < 8; ++nt) pool[nt] = 0.f;

    const int srr = (c & 3) * 16 + g * 4 + (c >> 2);   // swizzled A-frag read row

    #pragma unroll
    for (int grp = 0; grp < 2; ++grp) {
        const int m0 = grp * 2;
        if (amt[m0]) {
            const bool a1 = amt[m0 + 1];

            // ---------------- GEMM1 (2 M-tiles) ----------------
            f32x4 acc[2][8];
            #pragma unroll
            for (int ml = 0; ml < 2; ++ml)
                #pragma unroll
                for (int nt = 0; nt < 8; ++nt) acc[ml][nt] = (f32x4){0.f, 0.f, 0.f, 0.f};

            #pragma unroll
            for (int kt = 0; kt < 5; ++kt) {
                short8 af0, af1;
                if (kt < 4) {
                    af0 = *(const short8*)(emb16 + id[m0]     * 128 + kt * 32 + g * 8);
                    af1 = *(const short8*)(emb16 + id[m0 + 1] * 128 + kt * 32 + g * 8);
                } else { af0 = tfrag[m0]; af1 = tfrag[m0 + 1]; }
                #pragma unroll
                for (int nt = 0; nt < 8; ++nt) {
                    const short8 bf = ((const short8*)w1f)[(kt * 8 + nt) * 64 + lane];
                    acc[0][nt] = __builtin_amdgcn_mfma_f32_16x16x32_bf16(af0, bf, acc[0][nt], 0, 0, 0);
                    acc[1][nt] = __builtin_amdgcn_mfma_f32_16x16x32_bf16(af1, bf, acc[1][nt], 0, 0, 0);
                }
            }

            // ---------------- epilogue 1: +b1, LN1, GELU -> a2 (swizzled) ----------------
            {
                float l1wv[8], l1bv[8], bb1v[8];
                #pragma unroll
                for (int nt = 0; nt < 8; ++nt) {
                    l1wv[nt] = ln1w[nt * 16 + c]; l1bv[nt] = ln1b[nt * 16 + c]; bb1v[nt] = b1[nt * 16 + c];
                }
                #pragma unroll
                for (int ml = 0; ml < 2; ++ml) {
                    if (ml == 0 || a1) {
                        #pragma unroll
                        for (int r = 0; r < 4; ++r) {
                            float v[8], s = 0.f, q = 0.f;
                            #pragma unroll
                            for (int nt = 0; nt < 8; ++nt) {
                                v[nt] = acc[ml][nt][r] + bb1v[nt];
                                s += v[nt]; q = fmaf(v[nt], v[nt], q);
                            }
                            s += __shfl_xor(s, 1); q += __shfl_xor(q, 1);
                            s += __shfl_xor(s, 2); q += __shfl_xor(q, 2);
                            s += __shfl_xor(s, 4); q += __shfl_xor(q, 4);
                            s += __shfl_xor(s, 8); q += __shfl_xor(q, 8);
                            const float mean = s * (1.f / 128.f);
                            const float var  = fmaxf(q * (1.f / 128.f) - mean * mean, 0.f);
                            const float rstd = rsqrtf(var + LN_EPS);
                            #pragma unroll
                            for (int nt = 0; nt < 8; ++nt) {
                                const float y = fmaf((v[nt] - mean) * rstd, l1wv[nt], l1bv[nt]);
                                const unsigned short hv = f32_bf16_rne(gelu_f(y));
                                const int gk = (2 * nt + h3) & 3;
                                a2[ml][nt >> 1][r * 16 + gk * 4 + g][c & 7] = hv;
                            }
                        }
                    }
                }
            }

            // ---------------- GEMM2 ----------------
            f32x4 acc2[2][8];
            #pragma unroll
            for (int ml = 0; ml < 2; ++ml)
                #pragma unroll
                for (int nt = 0; nt < 8; ++nt) acc2[ml][nt] = (f32x4){0.f, 0.f, 0.f, 0.f};

            #pragma unroll
            for (int kt2 = 0; kt2 < 4; ++kt2) {
                short8 af0, af1;
                __builtin_memcpy(&af0, &a2[0][kt2][srr][0], 16);
                __builtin_memcpy(&af1, &a2[1][kt2][srr][0], 16);
                #pragma unroll
                for (int nt = 0; nt < 8; ++nt) {
                    const short8 bf = ((const short8*)w2f)[(kt2 * 8 + nt) * 64 + lane];
                    acc2[0][nt] = __builtin_amdgcn_mfma_f32_16x16x32_bf16(af0, bf, acc2[0][nt], 0, 0, 0);
                    acc2[1][nt] = __builtin_amdgcn_mfma_f32_16x16x32_bf16(af1, bf, acc2[1][nt], 0, 0, 0);
                }
            }

            // ---------------- epilogue 2: +b2, LN2, mask, pool ----------------
            {
                float l2wv[8], l2bv[8], bb2v[8];
                #pragma unroll
                for (int nt = 0; nt < 8; ++nt) {
                    l2wv[nt] = ln2w[nt * 16 + c]; l2bv[nt] = ln2b[nt * 16 + c]; bb2v[nt] = b2[nt * 16 + c];
                }
                #pragma unroll
                for (int ml = 0; ml < 2; ++ml) {
                    if (ml == 0 || a1) {
                        #pragma unroll
                        for (int r = 0; r < 4; ++r) {
                            float v[8], s = 0.f, q = 0.f;
                            #pragma unroll
                            for (int nt = 0; nt < 8; ++nt) {
                                v[nt] = acc2[ml][nt][r] + bb2v[nt];
                                s += v[nt]; q = fmaf(v[nt], v[nt], q);
                            }
                            s += __shfl_xor(s, 1); q += __shfl_xor(q, 1);
                            s += __shfl_xor(s, 2); q += __shfl_xor(q, 2);
                            s += __shfl_xor(s, 4); q += __shfl_xor(q, 4);
                            s += __shfl_xor(s, 8); q += __shfl_xor(q, 8);
                            const float mean = s * (1.f / 128.f);
                            const float var  = fmaxf(q * (1.f / 128.f) - mean * mean, 0.f);
                            const float rstd = rsqrtf(var + LN_EPS);
                            const int p = R0 + (m0 + ml) * 16 + 4 * g + r;
                            const float msk = (p < len) ? 1.f : 0.f;
                            #pragma unroll
                            for (int nt = 0; nt < 8; ++nt) {
                                const float y = fmaf((v[nt] - mean) * rstd, l2wv[nt], l2bv[nt]);
                                pool[nt] = fmaf(y, msk, pool[nt]);
                            }
                        }
                    }
                }
            }
        }
    }

    // pool: reduce across g groups, then one atomic per (lane c, nt)
    #pragma unroll
    for (int nt = 0; nt < 8; ++nt) {
        float t = pool[nt];
        t += __shfl_xor(t, 16);
        t += __shfl_xor(t, 32);
        pool[nt] = t;
    }
    if (g == 0) {
        const float inv = 1.f / (float)len;          // len >= 1 here
        #pragma unroll
        for (int nt = 0; nt < 8; ++nt)
            atomicAdd(&out[b * 128 + nt * 16 + c], pool[nt] * inv);
    }
}

extern "C" void kernel_launch(void* const* d_in, const int* in_sizes, int n_in,
                              void* d_out, int out_size, void* d_ws, size_t ws_size,
                              hipStream_t stream) {
    const int*   tids    = (const int*)  d_in[0];
    const float* dates   = (const float*)d_in[1];
    const int*   lengths = (const int*)  d_in[2];
    const float* emb     = (const float*)d_in[3];
    const float* tp_w    = (const float*)d_in[4];
    const float* tp_b    = (const float*)d_in[5];
    const float* tp_lnw  = (const float*)d_in[6];
    const float* tp_lnb  = (const float*)d_in[7];
    const float* w1      = (const float*)d_in[8];
    const float* b1      = (const float*)d_in[9];
    const float* ln1w    = (const float*)d_in[10];
    const float* ln1b    = (const float*)d_in[11];
    const float* w2      = (const float*)d_in[12];
    const float* b2      = (const float*)d_in[13];
    const float* ln2w    = (const float*)d_in[14];
    const float* ln2b    = (const float*)d_in[15];
    float* out = (float*)d_out;

    const int B = in_sizes[2];
    const int L = in_sizes[0] / B;
    const int emb_pairs = in_sizes[3] / 2;

    hipLaunchKernelGGL(prep_kernel, dim3(256), dim3(256), 0, stream,
                       w1, w2, emb, tp_w, tp_b, out, (unsigned*)d_ws, emb_pairs, out_size / 4);
    hipLaunchKernelGGL(encoder_mfma, dim3(B * 4), dim3(64), 0, stream,
                       tids, dates, lengths, tp_w, tp_b, tp_lnw, tp_lnb,
                       b1, ln1w, ln1b, b2, ln2w, ln2b,
                       (const unsigned*)d_ws, out, L);
}

// Round 4
// 280.997 us; speedup vs baseline: 1.1428x; 1.1428x over previous
//
#include <hip/hip_runtime.h>
#include <cmath>

#define LN_EPS 1e-5f

typedef float  f32x4  __attribute__((ext_vector_type(4)));
typedef short  short8 __attribute__((ext_vector_type(8)));
typedef unsigned int uint4v __attribute__((ext_vector_type(4)));

// ws layout (uint offsets):
//   w1f  : [0, 2560*4)          B-frag bf16 (5kt x 8nt x 64 lanes, uint4 each)
//   w2f  : [10240, 10240+2048*4) (4kt x 8nt x 64)
//   sums : uint 18432..18436     (Sw,Sb,Sww,Swb,Sbb)
//   emb16: uint 18440..          (NUM_TYPES*128 bf16, row-major)
#define W1F_U4 2560
#define W2F_U4 2048
#define SUMS_U 18432
#define EMB_U  18440

__device__ __forceinline__ unsigned short f32_bf16_rne(float f) {
    union { float f; unsigned u; } v; v.f = f;
    unsigned r = v.u + 0x7FFFu + ((v.u >> 16) & 1u);
    return (unsigned short)(r >> 16);
}

// exact-erf GELU via Abramowitz&Stegun 7.1.26 (|err| <= 1.5e-7)
__device__ __forceinline__ float gelu_f(float x) {
    float ax = fabsf(x);
    float a  = ax * 0.70710678118654752f;
    float t  = __builtin_amdgcn_rcpf(fmaf(0.3275911f, a, 1.0f));
    float p  = t * fmaf(t, fmaf(t, fmaf(t, fmaf(t, 1.061405429f, -1.453152027f),
                                        1.421413741f), -0.284496736f), 0.254829592f);
    float e  = __builtin_amdgcn_exp2f(-1.44269504089f * a * a);
    float E  = fmaf(-p, e, 1.0f);
    return 0.5f * fmaf(ax, E, x);
}

__global__ void prep_kernel(const float* __restrict__ w1, const float* __restrict__ w2,
                            const float* __restrict__ emb,
                            const float* __restrict__ tp_w, const float* __restrict__ tp_b,
                            float* __restrict__ out,
                            unsigned* __restrict__ ws, int emb_pairs, int out4) {
    const int tid = blockIdx.x * 256 + threadIdx.x;
    const int NT  = gridDim.x * 256;
    uint4v* w1f = (uint4v*)ws;
    uint4v* w2f = w1f + W1F_U4;
    float*  sums = (float*)(ws + SUMS_U);
    unsigned* emb16 = ws + EMB_U;

    for (int i = tid; i < W1F_U4; i += NT) {
        const int lane = i & 63, nt = (i >> 6) & 7, kt = i >> 9;
        const int k0 = kt * 32 + (lane >> 4) * 8, n = nt * 16 + (lane & 15);
        uint4v r;
        #pragma unroll
        for (int j2 = 0; j2 < 4; ++j2) {
            unsigned lo = f32_bf16_rne(w1[(k0 + 2 * j2) * 128 + n]);
            unsigned hi = f32_bf16_rne(w1[(k0 + 2 * j2 + 1) * 128 + n]);
            r[j2] = lo | (hi << 16);
        }
        w1f[i] = r;
    }
    for (int i = tid; i < W2F_U4; i += NT) {
        const int lane = i & 63, nt = (i >> 6) & 7, kt = i >> 9;
        const int k0 = kt * 32 + (lane >> 4) * 8, n = nt * 16 + (lane & 15);
        uint4v r;
        #pragma unroll
        for (int j2 = 0; j2 < 4; ++j2) {
            unsigned lo = f32_bf16_rne(w2[(k0 + 2 * j2) * 128 + n]);
            unsigned hi = f32_bf16_rne(w2[(k0 + 2 * j2 + 1) * 128 + n]);
            r[j2] = lo | (hi << 16);
        }
        w2f[i] = r;
    }
    for (int i = tid; i < emb_pairs; i += NT) {
        unsigned lo = f32_bf16_rne(emb[2 * i]);
        unsigned hi = f32_bf16_rne(emb[2 * i + 1]);
        emb16[i] = lo | (hi << 16);
    }
    f32x4 z = {0.f, 0.f, 0.f, 0.f};
    for (int i = tid; i < out4; i += NT) ((f32x4*)out)[i] = z;

    // temporal-LN closed-form sums, once
    if (blockIdx.x == 0 && threadIdx.x < 64) {
        const int lane = threadIdx.x;
        float w = 0.f, bb = 0.f;
        if (lane < 32) { w = tp_w[lane]; bb = tp_b[lane]; }
        float s0 = w, s1 = bb, s2 = w * w, s3 = w * bb, s4 = bb * bb;
        #pragma unroll
        for (int m = 1; m < 64; m <<= 1) {
            s0 += __shfl_xor(s0, m); s1 += __shfl_xor(s1, m);
            s2 += __shfl_xor(s2, m); s3 += __shfl_xor(s3, m); s4 += __shfl_xor(s4, m);
        }
        if (lane == 0) { sums[0] = s0; sums[1] = s1; sums[2] = s2; sums[3] = s3; sums[4] = s4; }
    }
}

// One wave (64 threads) per block; block bid handles row b = bid>>2, positions [64w, 64w+64).
// 2 groups of 2 M-tiles keeps peak accumulator footprint at 64 regs.
// launch_bounds(64,2): 256-reg budget -- R3's (64,3) forced a 170-reg budget and
// spilled the accumulators to scratch (WRITE_SIZE 130 MB). Do not lower this.
__global__ __launch_bounds__(64, 2) void encoder_mfma(
    const int*   __restrict__ tids,  const float* __restrict__ dates,
    const int*   __restrict__ lengths,
    const float* __restrict__ tp_w,  const float* __restrict__ tp_b,
    const float* __restrict__ tp_lnw,const float* __restrict__ tp_lnb,
    const float* __restrict__ b1,    const float* __restrict__ ln1w, const float* __restrict__ ln1b,
    const float* __restrict__ b2,    const float* __restrict__ ln2w, const float* __restrict__ ln2b,
    const unsigned* __restrict__ ws, float* __restrict__ out, int L)
{
    // C->A transpose scratch, bank-swizzled rows; reused across the 2 groups. 8 KB.
    __shared__ unsigned short a2[2][4][64][8];

    const int bid  = blockIdx.x;
    const int b    = bid >> 2, w = bid & 3;
    const int lane = threadIdx.x;
    const int c = lane & 15, g = lane >> 4, h3 = c >> 3;
    const int len = min(max(lengths[b], 0), L);
    const int R0 = w * 64;
    if (R0 >= len) return;

    const uint4v* w1f = (const uint4v*)ws;
    const uint4v* w2f = w1f + W1F_U4;
    const float*  sums = (const float*)(ws + SUMS_U);
    const unsigned short* emb16 = (const unsigned short*)(ws + EMB_U);

    const float Sw = sums[0], Sb = sums[1], Sww = sums[2], Swb = sums[3], Sbb = sums[4];

    int id[4]; float dn[4]; bool amt[4];
    #pragma unroll
    for (int mt = 0; mt < 4; ++mt) {
        const int p  = R0 + mt * 16 + c;
        const int pc = min(p, L - 1);
        id[mt]  = tids[b * L + pc];
        dn[mt]  = dates[b * L + pc] * (1.f / 1825.f);
        amt[mt] = (R0 + mt * 16) < len;              // wave-uniform, monotone in mt
    }

    // temporal A-frags (row=c, k-chunk g*8..g*8+7)
    short8 tfrag[4];
    {
        float tw[8], tb[8], tlw[8], tlb[8];
        const int j0 = g * 8;
        #pragma unroll
        for (int jj = 0; jj < 8; ++jj) {
            tw[jj] = tp_w[j0 + jj];  tb[jj] = tp_b[j0 + jj];
            tlw[jj] = tp_lnw[j0 + jj]; tlb[jj] = tp_lnb[j0 + jj];
        }
        #pragma unroll
        for (int mt = 0; mt < 4; ++mt) {
            const float d  = dn[mt];
            const float tm = fmaf(d, Sw, Sb) * (1.f / 32.f);
            float tv = fmaf(d * d, Sww, fmaf(2.f * d, Swb, Sbb)) * (1.f / 32.f) - tm * tm;
            const float trs = rsqrtf(fmaxf(tv, 0.f) + LN_EPS);
            uint4v r;
            #pragma unroll
            for (int j2 = 0; j2 < 4; ++j2) {
                const float y0 = fmaf((fmaf(d, tw[2*j2],   tb[2*j2])   - tm) * trs, tlw[2*j2],   tlb[2*j2]);
                const float y1 = fmaf((fmaf(d, tw[2*j2+1], tb[2*j2+1]) - tm) * trs, tlw[2*j2+1], tlb[2*j2+1]);
                r[j2] = (unsigned)f32_bf16_rne(gelu_f(y0)) | ((unsigned)f32_bf16_rne(gelu_f(y1)) << 16);
            }
            union { uint4v u; short8 s; } cv; cv.u = r;
            tfrag[mt] = cv.s;
        }
    }

    float pool[8];
    #pragma unroll
    for (int nt = 0; nt < 8; ++nt) pool[nt] = 0.f;

    const int srr = (c & 3) * 16 + g * 4 + (c >> 2);   // swizzled A-frag read row

    #pragma unroll
    for (int grp = 0; grp < 2; ++grp) {
        const int m0 = grp * 2;
        if (amt[m0]) {
            const bool a1 = amt[m0 + 1];

            // ---------------- GEMM1 (2 M-tiles) ----------------
            f32x4 acc[2][8];
            #pragma unroll
            for (int ml = 0; ml < 2; ++ml)
                #pragma unroll
                for (int nt = 0; nt < 8; ++nt) acc[ml][nt] = (f32x4){0.f, 0.f, 0.f, 0.f};

            #pragma unroll
            for (int kt = 0; kt < 5; ++kt) {
                short8 af0, af1;
                if (kt < 4) {
                    af0 = *(const short8*)(emb16 + id[m0]     * 128 + kt * 32 + g * 8);
                    af1 = *(const short8*)(emb16 + id[m0 + 1] * 128 + kt * 32 + g * 8);
                } else { af0 = tfrag[m0]; af1 = tfrag[m0 + 1]; }
                #pragma unroll
                for (int nt = 0; nt < 8; ++nt) {
                    const short8 bf = ((const short8*)w1f)[(kt * 8 + nt) * 64 + lane];
                    acc[0][nt] = __builtin_amdgcn_mfma_f32_16x16x32_bf16(af0, bf, acc[0][nt], 0, 0, 0);
                    acc[1][nt] = __builtin_amdgcn_mfma_f32_16x16x32_bf16(af1, bf, acc[1][nt], 0, 0, 0);
                }
            }

            // ---------------- epilogue 1: +b1, LN1, GELU -> a2 (swizzled) ----------------
            {
                float l1wv[8], l1bv[8], bb1v[8];
                #pragma unroll
                for (int nt = 0; nt < 8; ++nt) {
                    l1wv[nt] = ln1w[nt * 16 + c]; l1bv[nt] = ln1b[nt * 16 + c]; bb1v[nt] = b1[nt * 16 + c];
                }
                #pragma unroll
                for (int ml = 0; ml < 2; ++ml) {
                    if (ml == 0 || a1) {
                        #pragma unroll
                        for (int r = 0; r < 4; ++r) {
                            float v[8], s = 0.f, q = 0.f;
                            #pragma unroll
                            for (int nt = 0; nt < 8; ++nt) {
                                v[nt] = acc[ml][nt][r] + bb1v[nt];
                                s += v[nt]; q = fmaf(v[nt], v[nt], q);
                            }
                            s += __shfl_xor(s, 1); q += __shfl_xor(q, 1);
                            s += __shfl_xor(s, 2); q += __shfl_xor(q, 2);
                            s += __shfl_xor(s, 4); q += __shfl_xor(q, 4);
                            s += __shfl_xor(s, 8); q += __shfl_xor(q, 8);
                            const float mean = s * (1.f / 128.f);
                            const float var  = fmaxf(q * (1.f / 128.f) - mean * mean, 0.f);
                            const float rstd = rsqrtf(var + LN_EPS);
                            #pragma unroll
                            for (int nt = 0; nt < 8; ++nt) {
                                const float y = fmaf((v[nt] - mean) * rstd, l1wv[nt], l1bv[nt]);
                                const unsigned short hv = f32_bf16_rne(gelu_f(y));
                                const int gk = (2 * nt + h3) & 3;
                                a2[ml][nt >> 1][r * 16 + gk * 4 + g][c & 7] = hv;
                            }
                        }
                    }
                }
            }

            // ---------------- GEMM2 ----------------
            f32x4 acc2[2][8];
            #pragma unroll
            for (int ml = 0; ml < 2; ++ml)
                #pragma unroll
                for (int nt = 0; nt < 8; ++nt) acc2[ml][nt] = (f32x4){0.f, 0.f, 0.f, 0.f};

            #pragma unroll
            for (int kt2 = 0; kt2 < 4; ++kt2) {
                short8 af0, af1;
                __builtin_memcpy(&af0, &a2[0][kt2][srr][0], 16);
                __builtin_memcpy(&af1, &a2[1][kt2][srr][0], 16);
                #pragma unroll
                for (int nt = 0; nt < 8; ++nt) {
                    const short8 bf = ((const short8*)w2f)[(kt2 * 8 + nt) * 64 + lane];
                    acc2[0][nt] = __builtin_amdgcn_mfma_f32_16x16x32_bf16(af0, bf, acc2[0][nt], 0, 0, 0);
                    acc2[1][nt] = __builtin_amdgcn_mfma_f32_16x16x32_bf16(af1, bf, acc2[1][nt], 0, 0, 0);
                }
            }

            // ---------------- epilogue 2: +b2, LN2, mask, pool ----------------
            {
                float l2wv[8], l2bv[8], bb2v[8];
                #pragma unroll
                for (int nt = 0; nt < 8; ++nt) {
                    l2wv[nt] = ln2w[nt * 16 + c]; l2bv[nt] = ln2b[nt * 16 + c]; bb2v[nt] = b2[nt * 16 + c];
                }
                #pragma unroll
                for (int ml = 0; ml < 2; ++ml) {
                    if (ml == 0 || a1) {
                        #pragma unroll
                        for (int r = 0; r < 4; ++r) {
                            float v[8], s = 0.f, q = 0.f;
                            #pragma unroll
                            for (int nt = 0; nt < 8; ++nt) {
                                v[nt] = acc2[ml][nt][r] + bb2v[nt];
                                s += v[nt]; q = fmaf(v[nt], v[nt], q);
                            }
                            s += __shfl_xor(s, 1); q += __shfl_xor(q, 1);
                            s += __shfl_xor(s, 2); q += __shfl_xor(q, 2);
                            s += __shfl_xor(s, 4); q += __shfl_xor(q, 4);
                            s += __shfl_xor(s, 8); q += __shfl_xor(q, 8);
                            const float mean = s * (1.f / 128.f);
                            const float var  = fmaxf(q * (1.f / 128.f) - mean * mean, 0.f);
                            const float rstd = rsqrtf(var + LN_EPS);
                            const int p = R0 + (m0 + ml) * 16 + 4 * g + r;
                            const float msk = (p < len) ? 1.f : 0.f;
                            #pragma unroll
                            for (int nt = 0; nt < 8; ++nt) {
                                const float y = fmaf((v[nt] - mean) * rstd, l2wv[nt], l2bv[nt]);
                                pool[nt] = fmaf(y, msk, pool[nt]);
                            }
                        }
                    }
                }
            }
        }
    }

    // pool: reduce across g groups, then one atomic per (lane c, nt)
    #pragma unroll
    for (int nt = 0; nt < 8; ++nt) {
        float t = pool[nt];
        t += __shfl_xor(t, 16);
        t += __shfl_xor(t, 32);
        pool[nt] = t;
    }
    if (g == 0) {
        const float inv = 1.f / (float)len;          // len >= 1 here
        #pragma unroll
        for (int nt = 0; nt < 8; ++nt)
            atomicAdd(&out[b * 128 + nt * 16 + c], pool[nt] * inv);
    }
}

extern "C" void kernel_launch(void* const* d_in, const int* in_sizes, int n_in,
                              void* d_out, int out_size, void* d_ws, size_t ws_size,
                              hipStream_t stream) {
    const int*   tids    = (const int*)  d_in[0];
    const float* dates   = (const float*)d_in[1];
    const int*   lengths = (const int*)  d_in[2];
    const float* emb     = (const float*)d_in[3];
    const float* tp_w    = (const float*)d_in[4];
    const float* tp_b    = (const float*)d_in[5];
    const float* tp_lnw  = (const float*)d_in[6];
    const float* tp_lnb  = (const float*)d_in[7];
    const float* w1      = (const float*)d_in[8];
    const float* b1      = (const float*)d_in[9];
    const float* ln1w    = (const float*)d_in[10];
    const float* ln1b    = (const float*)d_in[11];
    const float* w2      = (const float*)d_in[12];
    const float* b2      = (const float*)d_in[13];
    const float* ln2w    = (const float*)d_in[14];
    const float* ln2b    = (const float*)d_in[15];
    float* out = (float*)d_out;

    const int B = in_sizes[2];
    const int L = in_sizes[0] / B;
    const int emb_pairs = in_sizes[3] / 2;

    hipLaunchKernelGGL(prep_kernel, dim3(256), dim3(256), 0, stream,
                       w1, w2, emb, tp_w, tp_b, out, (unsigned*)d_ws, emb_pairs, out_size / 4);
    hipLaunchKernelGGL(encoder_mfma, dim3(B * 4), dim3(64), 0, stream,
                       tids, dates, lengths, tp_w, tp_b, tp_lnw, tp_lnb,
                       b1, ln1w, ln1b, b2, ln2w, ln2b,
                       (const unsigned*)d_ws, out, L);
}